// Round 2
// baseline (1191.117 us; speedup 1.0000x reference)
//
#include <hip/hip_runtime.h>
#include <cstdint>
#include <cstddef>

typedef unsigned short ushort_t;
typedef __attribute__((ext_vector_type(8))) short short8;
typedef __attribute__((ext_vector_type(4))) short short4v;
typedef __attribute__((ext_vector_type(4))) float floatx4;

__device__ __forceinline__ float b2f(ushort_t u) {
    unsigned v = ((unsigned)u) << 16;
    return __builtin_bit_cast(float, v);
}
__device__ __forceinline__ float b2fs(short s) { return b2f((ushort_t)s); }
__device__ __forceinline__ ushort_t f2b(float f) {
    unsigned u = __builtin_bit_cast(unsigned, f);
    u += 0x7fffu + ((u >> 16) & 1u);   // RNE
    return (ushort_t)(u >> 16);
}

// ---------------------------------------------------------------------------
// fp32 -> bf16 bulk convert (8 elems/thread)
// ---------------------------------------------------------------------------
__global__ __launch_bounds__(256) void convert_kernel(
    const float* __restrict__ in, ushort_t* __restrict__ out, int n)
{
    int idx = (blockIdx.x * 256 + threadIdx.x) * 8;
    if (idx < n) {
        float4 a = *(const float4*)(in + idx);
        float4 b = *(const float4*)(in + idx + 4);
        short8 o;
        o[0] = (short)f2b(a.x); o[1] = (short)f2b(a.y);
        o[2] = (short)f2b(a.z); o[3] = (short)f2b(a.w);
        o[4] = (short)f2b(b.x); o[5] = (short)f2b(b.y);
        o[6] = (short)f2b(b.z); o[7] = (short)f2b(b.w);
        *(short8*)(out + idx) = o;
    }
}

// ---------------------------------------------------------------------------
// Generic bf16 GEMM: out[M,N] = A[M,K] @ B[K,N], B given transposed (BT[N,K]).
// 64x64 block tile, BK=64, 4 waves; wave w computes rows [w*16,w*16+16) x 64.
// ---------------------------------------------------------------------------
template <bool HAS_BIAS, bool DO_SILU>
__global__ __launch_bounds__(256) void gemm_kernel(
    const ushort_t* __restrict__ A, const ushort_t* __restrict__ BT,
    const float* __restrict__ bias, ushort_t* __restrict__ out,
    int M, int N, int K)
{
    __shared__ __align__(16) ushort_t As[64 * 72];   // pad +8: frag reads 2-way only (free)
    __shared__ __align__(16) ushort_t Bs[64 * 72];

    const int m0 = blockIdx.x * 64;
    const int n0 = blockIdx.y * 64;
    const int tid = threadIdx.x;
    const int w = tid >> 6;
    const int lane = tid & 63;
    const int quad = lane >> 4;
    const int r = lane & 15;

    floatx4 acc[4];
#pragma unroll
    for (int nt = 0; nt < 4; ++nt)
#pragma unroll
        for (int rg = 0; rg < 4; ++rg) acc[nt][rg] = 0.f;

    for (int k0 = 0; k0 < K; k0 += 64) {
        __syncthreads();
        // stage A (64x64) and BT (64x64): 512 chunks of 8 bf16, 2 per thread
#pragma unroll
        for (int it = 0; it < 2; ++it) {
            int c = tid + it * 256;
            int row = c >> 3;
            int col = (c & 7) << 3;
            short8 va = *(const short8*)(A + (size_t)(m0 + row) * K + (k0 + col));
            *(short8*)(As + row * 72 + col) = va;
            short8 vb = *(const short8*)(BT + (size_t)(n0 + row) * K + (k0 + col));
            *(short8*)(Bs + row * 72 + col) = vb;
        }
        __syncthreads();
#pragma unroll
        for (int ks = 0; ks < 2; ++ks) {
            short8 af = *(const short8*)(As + (w * 16 + r) * 72 + ks * 32 + quad * 8);
#pragma unroll
            for (int nt = 0; nt < 4; ++nt) {
                short8 bf_ = *(const short8*)(Bs + (nt * 16 + r) * 72 + ks * 32 + quad * 8);
                acc[nt] = __builtin_amdgcn_mfma_f32_16x16x32_bf16(af, bf_, acc[nt], 0, 0, 0);
            }
        }
    }

    // epilogue: D col = lane&15, row = quad*4 + reg
#pragma unroll
    for (int nt = 0; nt < 4; ++nt) {
        int col = n0 + nt * 16 + r;
        float bv = 0.f;
        if (HAS_BIAS) bv = bias[col];
#pragma unroll
        for (int rg = 0; rg < 4; ++rg) {
            int row = m0 + w * 16 + quad * 4 + rg;
            float v = acc[nt][rg] + bv;
            if (DO_SILU) v = v / (1.f + __expf(-v));
            out[(size_t)row * N + col] = f2b(v);
        }
    }
}

// ---------------------------------------------------------------------------
// LayerNorm over rows of 256: out = LN(y [+ res]) * g + b.  1 wave per row.
// y,res bf16; g,b fp32; out bf16 or fp32.
// ---------------------------------------------------------------------------
template <bool OUT_F32>
__global__ __launch_bounds__(256) void ln_kernel(
    const ushort_t* __restrict__ y, const ushort_t* __restrict__ res,
    const float* __restrict__ g, const float* __restrict__ b,
    void* __restrict__ outv)
{
    const int w = threadIdx.x >> 6;
    const int lane = threadIdx.x & 63;
    const size_t row = (size_t)blockIdx.x * 4 + w;
    const size_t base = row * 256 + lane * 4;

    short4v vy = *(const short4v*)(y + base);
    float v[4];
#pragma unroll
    for (int j = 0; j < 4; ++j) v[j] = b2fs(vy[j]);
    if (res) {
        short4v vr = *(const short4v*)(res + base);
#pragma unroll
        for (int j = 0; j < 4; ++j) v[j] += b2fs(vr[j]);
    }
    float s = v[0] + v[1] + v[2] + v[3];
    float sq = v[0] * v[0] + v[1] * v[1] + v[2] * v[2] + v[3] * v[3];
#pragma unroll
    for (int off = 32; off > 0; off >>= 1) {
        s += __shfl_xor(s, off, 64);
        sq += __shfl_xor(sq, off, 64);
    }
    float mean = s * (1.f / 256.f);
    float var = sq * (1.f / 256.f) - mean * mean;
    float rstd = rsqrtf(var + 1e-5f);
    if (OUT_F32) {
        float4 ov;
        int col = lane * 4;
        ov.x = (v[0] - mean) * rstd * g[col + 0] + b[col + 0];
        ov.y = (v[1] - mean) * rstd * g[col + 1] + b[col + 1];
        ov.z = (v[2] - mean) * rstd * g[col + 2] + b[col + 2];
        ov.w = (v[3] - mean) * rstd * g[col + 3] + b[col + 3];
        *(float4*)((float*)outv + base) = ov;
    } else {
        short4v ov;
#pragma unroll
        for (int j = 0; j < 4; ++j) {
            int col = lane * 4 + j;
            float o = (v[j] - mean) * rstd * g[col] + b[col];
            ov[j] = (short)f2b(o);
        }
        *(short4v*)((ushort_t*)outv + base) = ov;
    }
}

// ---------------------------------------------------------------------------
// Attention: one wave per token (8 positions x 8 heads x d=32).
// qkv rows for token are contiguous: [8][768] (q|k|v). lane = i*8+h.
// pos/Wpos/Wbias fp32; qkv & att_out bf16.
// ---------------------------------------------------------------------------
__global__ __launch_bounds__(256) void attn_kernel(
    const ushort_t* __restrict__ qkv,
    const float* __restrict__ pos1, const float* __restrict__ pos2,
    const float* __restrict__ Wpos, const float* __restrict__ Wbias,
    ushort_t* __restrict__ att_out)
{
    __shared__ __align__(16) ushort_t qkv_s[4][8 * 768];
    __shared__ float bias_s[4][8][8];   // [wave][key_nh][head]
    __shared__ float wpos_s[128];       // (4,32)
    __shared__ float wbias_s[256];      // (32,8)

    const int tid = threadIdx.x;
    if (tid < 128) wpos_s[tid] = Wpos[tid];
    wbias_s[tid] = Wbias[tid];

    const int w = tid >> 6;
    const int lane = tid & 63;
    const int tok = blockIdx.x * 4 + w;

    const ushort_t* src = qkv + (size_t)tok * 8 * 768;
    for (int c = lane; c < 768; c += 64)
        *(short8*)(qkv_s[w] + c * 8) = *(const short8*)(src + c * 8);
    __syncthreads();

    {   // positional bias: lane = j*8 + h
        const int j = lane >> 3, h = lane & 7;
        const size_t pbase = ((size_t)tok * 8 + j) * 2;
        float p0 = pos1[pbase], p1 = pos1[pbase + 1];
        float p2 = pos2[pbase], p3 = pos2[pbase + 1];
        float acc = 0.f;
#pragma unroll
        for (int p = 0; p < 32; ++p) {
            float e = p0 * wpos_s[p] + p1 * wpos_s[32 + p] + p2 * wpos_s[64 + p] + p3 * wpos_s[96 + p];
            e = e / (1.f + __expf(-e));             // silu
            acc += e * wbias_s[p * 8 + h];
        }
        bias_s[w][j][h] = acc;
    }
    __syncthreads();

    const int i = lane >> 3, h = lane & 7;
    const ushort_t* qrow = qkv_s[w] + i * 768 + h * 32;
    float q[32];
#pragma unroll
    for (int c = 0; c < 4; ++c) {
        short8 t8 = *(const short8*)(qrow + c * 8);
#pragma unroll
        for (int e = 0; e < 8; ++e) q[c * 8 + e] = b2fs(t8[e]);
    }
    float s[8];
#pragma unroll
    for (int jj = 0; jj < 8; ++jj) {
        const ushort_t* krow = qkv_s[w] + jj * 768 + 256 + h * 32;
        float d = 0.f;
#pragma unroll
        for (int c = 0; c < 4; ++c) {
            short8 t8 = *(const short8*)(krow + c * 8);
#pragma unroll
            for (int e = 0; e < 8; ++e) d += q[c * 8 + e] * b2fs(t8[e]);
        }
        s[jj] = d * 0.17677669529663688f + bias_s[w][jj][h];   // 1/sqrt(32)
    }
    float mx = s[0];
#pragma unroll
    for (int jj = 1; jj < 8; ++jj) mx = fmaxf(mx, s[jj]);
    float l = 0.f;
#pragma unroll
    for (int jj = 0; jj < 8; ++jj) { s[jj] = __expf(s[jj] - mx); l += s[jj]; }
    float rl = 1.f / l;
    float o[32];
#pragma unroll
    for (int e = 0; e < 32; ++e) o[e] = 0.f;
#pragma unroll
    for (int jj = 0; jj < 8; ++jj) {
        float p = s[jj] * rl;
        const ushort_t* vrow = qkv_s[w] + jj * 768 + 512 + h * 32;
#pragma unroll
        for (int c = 0; c < 4; ++c) {
            short8 t8 = *(const short8*)(vrow + c * 8);
#pragma unroll
            for (int e = 0; e < 8; ++e) o[c * 8 + e] += p * b2fs(t8[e]);
        }
    }
    ushort_t* orow = att_out + ((size_t)tok * 8 + i) * 256 + h * 32;
#pragma unroll
    for (int c = 0; c < 4; ++c) {
        short8 t8;
#pragma unroll
        for (int e = 0; e < 8; ++e) t8[e] = (short)f2b(o[c * 8 + e]);
        *(short8*)(orow + c * 8) = t8;
    }
}

// ---------------------------------------------------------------------------
// transpose + fp32->bf16 convert: in fp32 [K,N] -> out bf16 [N,K]
// ---------------------------------------------------------------------------
__global__ void transpose_kernel(const float* __restrict__ in,
                                 ushort_t* __restrict__ out, int K, int N)
{
    int idx = blockIdx.x * 256 + threadIdx.x;
    if (idx < K * N) {
        int k = idx / N, n = idx % N;
        out[n * K + k] = f2b(in[idx]);
    }
}

__global__ void pack_bias_kernel(const float* a, const float* b,
                                 const float* c, float* out)
{
    int t = blockIdx.x * 256 + threadIdx.x;
    if (t < 256) out[t] = a[t];
    else if (t < 512) out[t] = b[t - 256];
    else if (t < 768) out[t] = c[t - 512];
}

// ---------------------------------------------------------------------------
extern "C" void kernel_launch(void* const* d_in, const int* in_sizes, int n_in,
                              void* d_out, int out_size, void* d_ws, size_t ws_size,
                              hipStream_t stream)
{
    const float* x     = (const float*)d_in[0];
    const float* pos1  = (const float*)d_in[1];
    const float* pos2  = (const float*)d_in[2];
    const float* W_in  = (const float*)d_in[3];
    const float* g_in  = (const float*)d_in[4];
    const float* b_in  = (const float*)d_in[5];
    const float* Wq    = (const float*)d_in[6];
    const float* bq    = (const float*)d_in[7];
    const float* Wk    = (const float*)d_in[8];
    const float* bk    = (const float*)d_in[9];
    const float* Wv    = (const float*)d_in[10];
    const float* bv    = (const float*)d_in[11];
    const float* Wo    = (const float*)d_in[12];
    const float* bo    = (const float*)d_in[13];
    const float* W_pos = (const float*)d_in[14];
    const float* W_bias= (const float*)d_in[15];
    const float* W_ff1 = (const float*)d_in[16];
    const float* W_ff2 = (const float*)d_in[17];
    const float* g1    = (const float*)d_in[18];
    const float* b1    = (const float*)d_in[19];
    const float* g2    = (const float*)d_in[20];
    const float* b2    = (const float*)d_in[21];

    const int M = in_sizes[0] / 256;   // 131072 rows (b,n,nh)
    const int ntok = M / 8;            // 16384 tokens

    // workspace layout:
    //   header (2 MB): transposed bf16 weights + fp32 packed qkv bias
    //   bufA (M*256 bf16, 67 MB), bufB (M*256 bf16), bufC (M*1024 bf16, 268 MB)
    //   X16 and qkv live inside bufC (disjoint lifetimes). Total ~405 MB.
    ushort_t* ws    = (ushort_t*)d_ws;
    ushort_t* WinT  = ws;              // 256x256
    ushort_t* WqkvT = ws + 65536;      // 768x256
    ushort_t* WoT   = ws + 262144;     // 256x256
    ushort_t* Wff1T = ws + 327680;     // 1024x256
    ushort_t* Wff2T = ws + 589824;     // 256x1024
    float*    bqkv  = (float*)(ws + 851968);                    // 768 fp32
    ushort_t* bufA  = (ushort_t*)((char*)d_ws + (2ull << 20));  // M*256
    ushort_t* bufB  = bufA + (size_t)M * 256;                   // M*256
    ushort_t* bufC  = bufB + (size_t)M * 256;                   // M*1024

    transpose_kernel<<<256, 256, 0, stream>>>(W_in, WinT, 256, 256);
    transpose_kernel<<<256, 256, 0, stream>>>(Wq, WqkvT, 256, 256);
    transpose_kernel<<<256, 256, 0, stream>>>(Wk, WqkvT + 65536, 256, 256);
    transpose_kernel<<<256, 256, 0, stream>>>(Wv, WqkvT + 131072, 256, 256);
    transpose_kernel<<<256, 256, 0, stream>>>(Wo, WoT, 256, 256);
    transpose_kernel<<<1024, 256, 0, stream>>>(W_ff1, Wff1T, 256, 1024);
    transpose_kernel<<<1024, 256, 0, stream>>>(W_ff2, Wff2T, 1024, 256);
    pack_bias_kernel<<<3, 256, 0, stream>>>(bq, bk, bv, bqkv);

    dim3 blk(256);
    // x -> bf16 (into bufC; dead before qkv is written there)
    convert_kernel<<<(M * 256) / (256 * 8), blk, 0, stream>>>(x, bufC, M * 256);
    // y = x @ W_in
    gemm_kernel<false, false><<<dim3(M / 64, 4), blk, 0, stream>>>(bufC, WinT, nullptr, bufA, M, 256, 256);
    // t = LN(y)
    ln_kernel<false><<<M / 4, blk, 0, stream>>>(bufA, nullptr, g_in, b_in, bufB);
    // qkv = t @ [Wq|Wk|Wv] + [bq|bk|bv]
    gemm_kernel<true, false><<<dim3(M / 64, 12), blk, 0, stream>>>(bufB, WqkvT, bqkv, bufC, M, 768, 256);
    // att_out = attention(qkv, pos)
    attn_kernel<<<ntok / 4, blk, 0, stream>>>(bufC, pos1, pos2, W_pos, W_bias, bufA);
    // o = att_out @ Wo + bo   (into bufC; qkv dead)
    gemm_kernel<true, false><<<dim3(M / 64, 4), blk, 0, stream>>>(bufA, WoT, bo, bufC, M, 256, 256);
    // h1 = LN(o + t)
    ln_kernel<false><<<M / 4, blk, 0, stream>>>(bufC, bufB, g1, b1, bufA);
    // f = silu(h1 @ W_ff1)
    gemm_kernel<false, true><<<dim3(M / 64, 16), blk, 0, stream>>>(bufA, Wff1T, nullptr, bufC, M, 1024, 256);
    // f2 = f @ W_ff2
    gemm_kernel<false, false><<<dim3(M / 64, 4), blk, 0, stream>>>(bufC, Wff2T, nullptr, bufB, M, 256, 1024);
    // out = LN(f2 + h1)  -> fp32
    ln_kernel<true><<<M / 4, blk, 0, stream>>>(bufB, bufA, g2, b2, d_out);
}

// Round 3
// 1011.352 us; speedup vs baseline: 1.1777x; 1.1777x over previous
//
#include <hip/hip_runtime.h>
#include <cstdint>
#include <cstddef>

typedef unsigned short ushort_t;
typedef __attribute__((ext_vector_type(8))) short short8;
typedef __attribute__((ext_vector_type(4))) short short4v;
typedef __attribute__((ext_vector_type(4))) float floatx4;

__device__ __forceinline__ float b2f(ushort_t u) {
    unsigned v = ((unsigned)u) << 16;
    return __builtin_bit_cast(float, v);
}
__device__ __forceinline__ float b2fs(short s) { return b2f((ushort_t)s); }
__device__ __forceinline__ ushort_t f2b(float f) {
    unsigned u = __builtin_bit_cast(unsigned, f);
    u += 0x7fffu + ((u >> 16) & 1u);   // RNE
    return (ushort_t)(u >> 16);
}

// async global->LDS, 16B per lane; lds base must be wave-uniform (HW adds lane*16)
__device__ __forceinline__ void load_lds16(const ushort_t* g, ushort_t* l) {
    __builtin_amdgcn_global_load_lds(
        (const __attribute__((address_space(1))) void*)g,
        (__attribute__((address_space(3))) void*)l, 16, 0, 0);
}

// ---------------------------------------------------------------------------
// Strip GEMM, K=256: block = 128 A-rows resident in LDS for the whole kernel;
// loop NT n-tiles of 128 cols, restaging only B (16KB per K-chunk).
// out[M, NT*128] = A[M,256] @ BT[NT*128,256]^T (+bias, silu optional).
// LDS 80KB -> 2 blocks/CU. A read from HBM exactly once.
// ---------------------------------------------------------------------------
template <int NT, bool A_F32, bool HAS_BIAS, bool DO_SILU>
__global__ __launch_bounds__(256, 2) void gemm_strip(
    const void* __restrict__ Ap, const ushort_t* __restrict__ BT,
    const float* __restrict__ bias, ushort_t* __restrict__ out)
{
    constexpr int K = 256;
    constexpr int ldN = NT * 128;
    __shared__ __align__(16) ushort_t As[128 * 256];   // 64 KB, unpadded (load_lds order)
    __shared__ __align__(16) ushort_t Bs[128 * 64];    // 16 KB

    const int tid = threadIdx.x;
    const int w = tid >> 6, lane = tid & 63;
    const int wm = w >> 1, wn = w & 1;
    const int quad = lane >> 4, r = lane & 15;
    const size_t m0 = (size_t)blockIdx.x * 128;

    if (A_F32) {
        // fused fp32->bf16 convert while staging the A panel
        const float* A = (const float*)Ap;
#pragma unroll
        for (int it = 0; it < 16; ++it) {
            int c = it * 256 + tid;            // 4096 chunks of 8 floats
            int row = c >> 5, col = (c & 31) * 8;
            const float* p = A + (m0 + row) * K + col;
            float4 a = *(const float4*)p;
            float4 b = *(const float4*)(p + 4);
            short8 o;
            o[0] = (short)f2b(a.x); o[1] = (short)f2b(a.y);
            o[2] = (short)f2b(a.z); o[3] = (short)f2b(a.w);
            o[4] = (short)f2b(b.x); o[5] = (short)f2b(b.y);
            o[6] = (short)f2b(b.z); o[7] = (short)f2b(b.w);
            *(short8*)(As + row * 256 + col) = o;
        }
    } else {
        const ushort_t* A = (const ushort_t*)Ap;
#pragma unroll
        for (int it = 0; it < 16; ++it) {      // 16 x 4KB = 64KB; wave covers 2 rows/issue
            int row = it * 8 + w * 2 + (lane >> 5);
            load_lds16(A + (m0 + row) * K + (lane & 31) * 8,
                       As + (it * 8 + w * 2) * 256);
        }
    }

    for (int nt_i = 0; nt_i < NT; ++nt_i) {
        const int n0 = nt_i * 128;
        floatx4 acc[4][4];
#pragma unroll
        for (int nt = 0; nt < 4; ++nt)
#pragma unroll
            for (int mt = 0; mt < 4; ++mt)
#pragma unroll
                for (int rg = 0; rg < 4; ++rg) acc[nt][mt][rg] = 0.f;

#pragma unroll
        for (int kc = 0; kc < 4; ++kc) {
            __syncthreads();                   // Bs free (also drains A staging on 1st iter)
#pragma unroll
            for (int i = 0; i < 4; ++i) {      // 4 x 4KB; wave covers 8 rows/issue
                int row = i * 32 + w * 8 + (lane >> 3);
                load_lds16(BT + (size_t)(n0 + row) * K + kc * 64 + (lane & 7) * 8,
                           Bs + (i * 32 + w * 8) * 64);
            }
            __syncthreads();                   // staging complete
#pragma unroll
            for (int ks = 0; ks < 2; ++ks) {
                short8 af[4];
#pragma unroll
                for (int mt = 0; mt < 4; ++mt)
                    af[mt] = *(const short8*)(As + (wm * 64 + mt * 16 + r) * 256
                                              + kc * 64 + ks * 32 + quad * 8);
#pragma unroll
                for (int nt = 0; nt < 4; ++nt) {
                    short8 bf_ = *(const short8*)(Bs + (wn * 64 + nt * 16 + r) * 64
                                                  + ks * 32 + quad * 8);
#pragma unroll
                    for (int mt = 0; mt < 4; ++mt)
                        acc[nt][mt] = __builtin_amdgcn_mfma_f32_16x16x32_bf16(
                            af[mt], bf_, acc[nt][mt], 0, 0, 0);
                }
            }
        }
        // epilogue: D col = lane&15, row = quad*4 + reg
#pragma unroll
        for (int nt = 0; nt < 4; ++nt) {
            int col = n0 + wn * 64 + nt * 16 + r;
            float bv = 0.f;
            if (HAS_BIAS) bv = bias[col];
#pragma unroll
            for (int mt = 0; mt < 4; ++mt) {
#pragma unroll
                for (int rg = 0; rg < 4; ++rg) {
                    size_t row = m0 + wm * 64 + mt * 16 + quad * 4 + rg;
                    float v = acc[nt][mt][rg] + bv;
                    if (DO_SILU) v = v / (1.f + __expf(-v));
                    out[row * ldN + col] = f2b(v);
                }
            }
        }
    }
}

// ---------------------------------------------------------------------------
// Wide GEMM for FF2: K=1024, N=256. 128x256 block tile (full N) -> A read once.
// acc[8][4] = 128 AGPRs/lane; LDS 48KB.
// ---------------------------------------------------------------------------
__global__ __launch_bounds__(256, 2) void gemm_wide(
    const ushort_t* __restrict__ A, const ushort_t* __restrict__ BT,
    ushort_t* __restrict__ out)
{
    constexpr int K = 1024, N = 256;
    __shared__ __align__(16) ushort_t As[128 * 64];   // 16 KB
    __shared__ __align__(16) ushort_t Bs[256 * 64];   // 32 KB

    const int tid = threadIdx.x;
    const int w = tid >> 6, lane = tid & 63;
    const int wm = w >> 1, wn = w & 1;
    const int quad = lane >> 4, r = lane & 15;
    const size_t m0 = (size_t)blockIdx.x * 128;

    floatx4 acc[8][4];
#pragma unroll
    for (int nt = 0; nt < 8; ++nt)
#pragma unroll
        for (int mt = 0; mt < 4; ++mt)
#pragma unroll
            for (int rg = 0; rg < 4; ++rg) acc[nt][mt][rg] = 0.f;

    for (int kc = 0; kc < K / 64; ++kc) {
        __syncthreads();
#pragma unroll
        for (int i = 0; i < 4; ++i) {
            int row = i * 32 + w * 8 + (lane >> 3);
            load_lds16(A + (m0 + row) * K + kc * 64 + (lane & 7) * 8,
                       As + (i * 32 + w * 8) * 64);
        }
#pragma unroll
        for (int i = 0; i < 8; ++i) {
            int row = i * 32 + w * 8 + (lane >> 3);
            load_lds16(BT + (size_t)row * K + kc * 64 + (lane & 7) * 8,
                       Bs + (i * 32 + w * 8) * 64);
        }
        __syncthreads();
#pragma unroll
        for (int ks = 0; ks < 2; ++ks) {
            short8 af[4];
#pragma unroll
            for (int mt = 0; mt < 4; ++mt)
                af[mt] = *(const short8*)(As + (wm * 64 + mt * 16 + r) * 64
                                          + ks * 32 + quad * 8);
#pragma unroll
            for (int nt = 0; nt < 8; ++nt) {
                short8 bf_ = *(const short8*)(Bs + (wn * 128 + nt * 16 + r) * 64
                                              + ks * 32 + quad * 8);
#pragma unroll
                for (int mt = 0; mt < 4; ++mt)
                    acc[nt][mt] = __builtin_amdgcn_mfma_f32_16x16x32_bf16(
                        af[mt], bf_, acc[nt][mt], 0, 0, 0);
            }
        }
    }
#pragma unroll
    for (int nt = 0; nt < 8; ++nt) {
        int col = wn * 128 + nt * 16 + r;
#pragma unroll
        for (int mt = 0; mt < 4; ++mt)
#pragma unroll
            for (int rg = 0; rg < 4; ++rg) {
                size_t row = m0 + wm * 64 + mt * 16 + quad * 4 + rg;
                out[row * N + col] = f2b(acc[nt][mt][rg]);
            }
    }
}

// ---------------------------------------------------------------------------
// LayerNorm over rows of 256: out = LN(y [+ res]) * g + b.  1 wave per row.
// ---------------------------------------------------------------------------
template <bool OUT_F32>
__global__ __launch_bounds__(256) void ln_kernel(
    const ushort_t* __restrict__ y, const ushort_t* __restrict__ res,
    const float* __restrict__ g, const float* __restrict__ b,
    void* __restrict__ outv)
{
    const int w = threadIdx.x >> 6;
    const int lane = threadIdx.x & 63;
    const size_t row = (size_t)blockIdx.x * 4 + w;
    const size_t base = row * 256 + lane * 4;

    short4v vy = *(const short4v*)(y + base);
    float v[4];
#pragma unroll
    for (int j = 0; j < 4; ++j) v[j] = b2fs(vy[j]);
    if (res) {
        short4v vr = *(const short4v*)(res + base);
#pragma unroll
        for (int j = 0; j < 4; ++j) v[j] += b2fs(vr[j]);
    }
    float s = v[0] + v[1] + v[2] + v[3];
    float sq = v[0] * v[0] + v[1] * v[1] + v[2] * v[2] + v[3] * v[3];
#pragma unroll
    for (int off = 32; off > 0; off >>= 1) {
        s += __shfl_xor(s, off, 64);
        sq += __shfl_xor(sq, off, 64);
    }
    float mean = s * (1.f / 256.f);
    float var = sq * (1.f / 256.f) - mean * mean;
    float rstd = rsqrtf(var + 1e-5f);
    if (OUT_F32) {
        float4 ov;
        int col = lane * 4;
        ov.x = (v[0] - mean) * rstd * g[col + 0] + b[col + 0];
        ov.y = (v[1] - mean) * rstd * g[col + 1] + b[col + 1];
        ov.z = (v[2] - mean) * rstd * g[col + 2] + b[col + 2];
        ov.w = (v[3] - mean) * rstd * g[col + 3] + b[col + 3];
        *(float4*)((float*)outv + base) = ov;
    } else {
        short4v ov;
#pragma unroll
        for (int j = 0; j < 4; ++j) {
            int col = lane * 4 + j;
            float o = (v[j] - mean) * rstd * g[col] + b[col];
            ov[j] = (short)f2b(o);
        }
        *(short4v*)((ushort_t*)outv + base) = ov;
    }
}

// ---------------------------------------------------------------------------
// Attention: one wave per token (8 positions x 8 heads x d=32).
// ---------------------------------------------------------------------------
__global__ __launch_bounds__(256) void attn_kernel(
    const ushort_t* __restrict__ qkv,
    const float* __restrict__ pos1, const float* __restrict__ pos2,
    const float* __restrict__ Wpos, const float* __restrict__ Wbias,
    ushort_t* __restrict__ att_out)
{
    __shared__ __align__(16) ushort_t qkv_s[4][8 * 768];
    __shared__ float bias_s[4][8][8];
    __shared__ float wpos_s[128];
    __shared__ float wbias_s[256];

    const int tid = threadIdx.x;
    if (tid < 128) wpos_s[tid] = Wpos[tid];
    wbias_s[tid] = Wbias[tid];

    const int w = tid >> 6;
    const int lane = tid & 63;
    const int tok = blockIdx.x * 4 + w;

    const ushort_t* src = qkv + (size_t)tok * 8 * 768;
    for (int c = lane; c < 768; c += 64)
        *(short8*)(qkv_s[w] + c * 8) = *(const short8*)(src + c * 8);
    __syncthreads();

    {   // positional bias: lane = j*8 + h
        const int j = lane >> 3, h = lane & 7;
        const size_t pbase = ((size_t)tok * 8 + j) * 2;
        float p0 = pos1[pbase], p1 = pos1[pbase + 1];
        float p2 = pos2[pbase], p3 = pos2[pbase + 1];
        float acc = 0.f;
#pragma unroll
        for (int p = 0; p < 32; ++p) {
            float e = p0 * wpos_s[p] + p1 * wpos_s[32 + p] + p2 * wpos_s[64 + p] + p3 * wpos_s[96 + p];
            e = e / (1.f + __expf(-e));
            acc += e * wbias_s[p * 8 + h];
        }
        bias_s[w][j][h] = acc;
    }
    __syncthreads();

    const int i = lane >> 3, h = lane & 7;
    const ushort_t* qrow = qkv_s[w] + i * 768 + h * 32;
    float q[32];
#pragma unroll
    for (int c = 0; c < 4; ++c) {
        short8 t8 = *(const short8*)(qrow + c * 8);
#pragma unroll
        for (int e = 0; e < 8; ++e) q[c * 8 + e] = b2fs(t8[e]);
    }
    float s[8];
#pragma unroll
    for (int jj = 0; jj < 8; ++jj) {
        const ushort_t* krow = qkv_s[w] + jj * 768 + 256 + h * 32;
        float d = 0.f;
#pragma unroll
        for (int c = 0; c < 4; ++c) {
            short8 t8 = *(const short8*)(krow + c * 8);
#pragma unroll
            for (int e = 0; e < 8; ++e) d += q[c * 8 + e] * b2fs(t8[e]);
        }
        s[jj] = d * 0.17677669529663688f + bias_s[w][jj][h];
    }
    float mx = s[0];
#pragma unroll
    for (int jj = 1; jj < 8; ++jj) mx = fmaxf(mx, s[jj]);
    float l = 0.f;
#pragma unroll
    for (int jj = 0; jj < 8; ++jj) { s[jj] = __expf(s[jj] - mx); l += s[jj]; }
    float rl = 1.f / l;
    float o[32];
#pragma unroll
    for (int e = 0; e < 32; ++e) o[e] = 0.f;
#pragma unroll
    for (int jj = 0; jj < 8; ++jj) {
        float p = s[jj] * rl;
        const ushort_t* vrow = qkv_s[w] + jj * 768 + 512 + h * 32;
#pragma unroll
        for (int c = 0; c < 4; ++c) {
            short8 t8 = *(const short8*)(vrow + c * 8);
#pragma unroll
            for (int e = 0; e < 8; ++e) o[c * 8 + e] += p * b2fs(t8[e]);
        }
    }
    ushort_t* orow = att_out + ((size_t)tok * 8 + i) * 256 + h * 32;
#pragma unroll
    for (int c = 0; c < 4; ++c) {
        short8 t8;
#pragma unroll
        for (int e = 0; e < 8; ++e) t8[e] = (short)f2b(o[c * 8 + e]);
        *(short8*)(orow + c * 8) = t8;
    }
}

// ---------------------------------------------------------------------------
__global__ void transpose_kernel(const float* __restrict__ in,
                                 ushort_t* __restrict__ out, int K, int N)
{
    int idx = blockIdx.x * 256 + threadIdx.x;
    if (idx < K * N) {
        int k = idx / N, n = idx % N;
        out[n * K + k] = f2b(in[idx]);
    }
}

__global__ void pack_bias_kernel(const float* a, const float* b,
                                 const float* c, float* out)
{
    int t = blockIdx.x * 256 + threadIdx.x;
    if (t < 256) out[t] = a[t];
    else if (t < 512) out[t] = b[t - 256];
    else if (t < 768) out[t] = c[t - 512];
}

// ---------------------------------------------------------------------------
extern "C" void kernel_launch(void* const* d_in, const int* in_sizes, int n_in,
                              void* d_out, int out_size, void* d_ws, size_t ws_size,
                              hipStream_t stream)
{
    const float* x     = (const float*)d_in[0];
    const float* pos1  = (const float*)d_in[1];
    const float* pos2  = (const float*)d_in[2];
    const float* W_in  = (const float*)d_in[3];
    const float* g_in  = (const float*)d_in[4];
    const float* b_in  = (const float*)d_in[5];
    const float* Wq    = (const float*)d_in[6];
    const float* bq    = (const float*)d_in[7];
    const float* Wk    = (const float*)d_in[8];
    const float* bk    = (const float*)d_in[9];
    const float* Wv    = (const float*)d_in[10];
    const float* bv    = (const float*)d_in[11];
    const float* Wo    = (const float*)d_in[12];
    const float* bo    = (const float*)d_in[13];
    const float* W_pos = (const float*)d_in[14];
    const float* W_bias= (const float*)d_in[15];
    const float* W_ff1 = (const float*)d_in[16];
    const float* W_ff2 = (const float*)d_in[17];
    const float* g1    = (const float*)d_in[18];
    const float* b1    = (const float*)d_in[19];
    const float* g2    = (const float*)d_in[20];
    const float* b2    = (const float*)d_in[21];

    const int M = in_sizes[0] / 256;   // 131072 rows (b,n,nh)
    const int ntok = M / 8;            // 16384 tokens

    // ws: 2MB header (bf16 weights^T + fp32 qkv bias) then big buffers
    ushort_t* ws    = (ushort_t*)d_ws;
    ushort_t* WinT  = ws;              // 256x256
    ushort_t* WqkvT = ws + 65536;      // 768x256
    ushort_t* WoT   = ws + 262144;     // 256x256
    ushort_t* Wff1T = ws + 327680;     // 1024x256
    ushort_t* Wff2T = ws + 589824;     // 256x1024
    float*    bqkv  = (float*)(ws + 851968);                    // 768 fp32
    ushort_t* bufA  = (ushort_t*)((char*)d_ws + (2ull << 20));  // M*256
    ushort_t* bufB  = bufA + (size_t)M * 256;                   // M*256
    ushort_t* bufC  = bufB + (size_t)M * 256;                   // M*1024

    transpose_kernel<<<256, 256, 0, stream>>>(W_in, WinT, 256, 256);
    transpose_kernel<<<256, 256, 0, stream>>>(Wq, WqkvT, 256, 256);
    transpose_kernel<<<256, 256, 0, stream>>>(Wk, WqkvT + 65536, 256, 256);
    transpose_kernel<<<256, 256, 0, stream>>>(Wv, WqkvT + 131072, 256, 256);
    transpose_kernel<<<256, 256, 0, stream>>>(Wo, WoT, 256, 256);
    transpose_kernel<<<1024, 256, 0, stream>>>(W_ff1, Wff1T, 256, 1024);
    transpose_kernel<<<1024, 256, 0, stream>>>(W_ff2, Wff2T, 1024, 256);
    pack_bias_kernel<<<3, 256, 0, stream>>>(bq, bk, bv, bqkv);

    dim3 blk(256);
    // y = x @ W_in      (fp32 A fused-converted during staging)
    gemm_strip<2, true, false, false><<<M / 128, blk, 0, stream>>>(x, WinT, nullptr, bufA);
    // t = LN(y)
    ln_kernel<false><<<M / 4, blk, 0, stream>>>(bufA, nullptr, g_in, b_in, bufB);
    // qkv = t @ [Wq|Wk|Wv] + [bq|bk|bv]
    gemm_strip<6, false, true, false><<<M / 128, blk, 0, stream>>>(bufB, WqkvT, bqkv, bufC);
    // att_out = attention(qkv, pos)
    attn_kernel<<<ntok / 4, blk, 0, stream>>>(bufC, pos1, pos2, W_pos, W_bias, bufA);
    // o = att_out @ Wo + bo
    gemm_strip<2, false, true, false><<<M / 128, blk, 0, stream>>>(bufA, WoT, bo, bufC);
    // h1 = LN(o + t)
    ln_kernel<false><<<M / 4, blk, 0, stream>>>(bufC, bufB, g1, b1, bufA);
    // f = silu(h1 @ W_ff1)
    gemm_strip<8, false, false, true><<<M / 128, blk, 0, stream>>>(bufA, Wff1T, nullptr, bufC);
    // f2 = f @ W_ff2   (wide: full N per block, A read once)
    gemm_wide<<<M / 128, blk, 0, stream>>>(bufC, Wff2T, bufB);
    // out = LN(f2 + h1) -> fp32
    ln_kernel<true><<<M / 4, blk, 0, stream>>>(bufB, bufA, g2, b2, d_out);
}